// Round 7
// baseline (780.359 us; speedup 1.0000x reference)
//
#include <hip/hip_runtime.h>
#include <stdint.h>

#define BB    4
#define NQ    8192
#define NS    4096
#define FDIM  256
#define KNN   8

typedef unsigned long long u64;

// ---------------- cell grid parameters ----------------
#define GD     16                 // cells per axis
#define GMINF  (-4.25f)
#define HF     (0.53125f)         // 8.5/16, exact in f32
#define INVHF  (1.882352941176f)  // 1/HF (consistent everywhere)

__device__ __forceinline__ int cix(float v) {
    int c = (int)floorf((v - GMINF) * INVHF);
    return c < 0 ? 0 : (c > GD - 1 ? GD - 1 : c);
}

// Selection key x' = s^2 - 2 q.s (= d^2 - q^2). Fixed rounding ops so pass 1
// and pass 2 compute bit-identical values (threshold membership is exact).
#define KEYX(m) __fmaf_rn(qx, (m).x, __fmaf_rn(qy, (m).y, __fmaf_rn(qz, (m).z, (m).w)))

__device__ __forceinline__ float med3(float a, float b, float c) {
    return __builtin_amdgcn_fmed3f(a, b, c);
}

// ---------------- d_ws layout ----------------
// starts : 4100 ints   @ 0        (exclusive prefix, starts[4096]=NS)
// table  : 4096 float4 @ 16400    ((-2x,-2y,-2z,s^2), cell-sorted)
// oidx   : 4096 ints   @ 81936    (original sensor index, cell-sorted)
#define WS_STARTS   0
#define WS_TABLE    16400
#define WS_OIDX     81936
#define WS_NEED     98320

// ================= build kernel: histogram -> scan -> scatter =================
__global__ __launch_bounds__(1024, 1) void build_grid(
    const float* __restrict__ sc, int* __restrict__ starts,
    float4* __restrict__ tbl, int* __restrict__ oidx)
{
    __shared__ int h[GD * GD * GD];     // 16 KB
    __shared__ int cur[GD * GD * GD];   // 16 KB
    __shared__ int wtot[16];

    const int tid = threadIdx.x;
    for (int c = tid; c < GD * GD * GD; c += 1024) h[c] = 0;
    __syncthreads();

    for (int s = tid; s < NS; s += 1024) {
        const int cell = (cix(sc[3*s+2]) * GD + cix(sc[3*s+1])) * GD + cix(sc[3*s+0]);
        atomicAdd(&h[cell], 1);
    }
    __syncthreads();

    // exclusive scan of h[4096]: thread t owns 4 consecutive cells
    const int lane = tid & 63, wid = tid >> 6;
    const int c0 = tid * 4;
    const int a = h[c0], b1 = h[c0+1], c2 = h[c0+2], d3 = h[c0+3];
    const int tsum = a + b1 + c2 + d3;
    int inc = tsum;
    #pragma unroll
    for (int d = 1; d <= 32; d <<= 1) {
        const int o = __shfl_up(inc, d, 64);
        if (lane >= d) inc += o;
    }
    if (lane == 63) wtot[wid] = inc;
    __syncthreads();
    if (tid == 0) {
        int acc = 0;
        #pragma unroll
        for (int w = 0; w < 16; ++w) { const int t = wtot[w]; wtot[w] = acc; acc += t; }
    }
    __syncthreads();
    int base = wtot[wid] + (inc - tsum);
    starts[c0]   = base;          cur[c0]   = base;   base += a;
    starts[c0+1] = base;          cur[c0+1] = base;   base += b1;
    starts[c0+2] = base;          cur[c0+2] = base;   base += c2;
    starts[c0+3] = base;          cur[c0+3] = base;
    if (tid == 0) starts[GD * GD * GD] = NS;
    __syncthreads();

    for (int s = tid; s < NS; s += 1024) {
        const float sx = sc[3*s+0], sy = sc[3*s+1], sz = sc[3*s+2];
        const int cell = (cix(sz) * GD + cix(sy)) * GD + cix(sx);
        const int pos = atomicAdd(&cur[cell], 1);
        const float s2 = __fmaf_rn(sx, sx, __fmaf_rn(sy, sy, __fmul_rn(sz, sz)));
        tbl[pos]  = make_float4(-2.0f*sx, -2.0f*sy, -2.0f*sz, s2);
        oidx[pos] = s;
    }
}

// ================= main kernel: per-lane kNN + full-wave gather =================
#define QPB 16   // queries per block (one per lane, lanes 0..15)

__global__ __launch_bounds__(64, 4) void knn_gather(
    const float* __restrict__ qc, const float* __restrict__ sf,
    const int* __restrict__ starts, const float4* __restrict__ tbl,
    const int* __restrict__ oidx, float* __restrict__ out)
{
    __shared__ int   s_pid[QPB][KNN];
    __shared__ float s_pw[QPB][KNN];

    const int tid = threadIdx.x;

    // XCD swizzle: batch b -> XCD pair {2b,2b+1}; bijective over 2048 blocks.
    const int p   = blockIdx.x;
    const int xcd = p & 7;
    const int b   = xcd >> 1;
    const int sub = ((p >> 3) << 1) | (xcd & 1);    // 0..511
    const int q0  = b * NQ + sub * QPB;

    if (tid < QPB) {
        const float* qp = qc + (size_t)(q0 + tid) * 3;
        const float qx = qp[0], qy = qp[1], qz = qp[2];
        const float q2 = __fmaf_rn(qx, qx, __fmaf_rn(qy, qy, __fmul_rn(qz, qz)));
        const int cqx = cix(qx), cqy = cix(qy), cqz = cix(qz);

        // ---- pass 1: value-only top-8 of x' over expanding cell rings ----
        float kd[KNN];
        #pragma unroll
        for (int j = 0; j < KNN; ++j) kd[j] = 3.4e38f;

        int Rdone = GD - 1;
        bool done = false;
        for (int R = 0; R < GD; ++R) {
            if (!done) {
                for (int dz = -R; dz <= R; ++dz) {
                    const int cz = cqz + dz;
                    if ((unsigned)cz >= GD) continue;
                    const int az = dz < 0 ? -dz : dz;
                    for (int dy = -R; dy <= R; ++dy) {
                        const int cy = cqy + dy;
                        if ((unsigned)cy >= GD) continue;
                        const int ay = dy < 0 ? -dy : dy;
                        const int azy = az > ay ? az : ay;
                        for (int dx = -R; dx <= R; ++dx) {
                            const int ax = dx < 0 ? -dx : dx;
                            if ((azy > ax ? azy : ax) != R) continue;
                            const int cx = cqx + dx;
                            if ((unsigned)cx >= GD) continue;
                            const int cell = (cz * GD + cy) * GD + cx;
                            const int s0 = starts[cell], e0 = starts[cell + 1];
                            for (int j = s0; j < e0; ++j) {
                                const float4 m = tbl[j];
                                const float x = KEYX(m);
                                const float nk0 = fminf(kd[0], x);
                                #pragma unroll
                                for (int jj = KNN - 1; jj >= 1; --jj)
                                    kd[jj] = med3(kd[jj-1], kd[jj], x);
                                kd[0] = nk0;
                            }
                        }
                    }
                }
                const float d8sq = fmaxf(__fadd_rn(kd[KNN-1], q2), 0.0f);
                const float lim  = (float)R * HF - 1e-4f;
                if (R >= 1 && d8sq <= lim * lim) { done = true; Rdone = R; }
            }
            if (__all(done)) break;
        }
        const float thrv = kd[KNN - 1];

        // ---- pass 2: membership re-scan of rings 0..Rdone, collect (d^2,idx) ----
        u64 k8[KNN];
        #pragma unroll
        for (int j = 0; j < KNN; ++j) k8[j] = ~0ull;

        for (int R = 0; R < GD; ++R) {
            if (R <= Rdone) {
                for (int dz = -R; dz <= R; ++dz) {
                    const int cz = cqz + dz;
                    if ((unsigned)cz >= GD) continue;
                    const int az = dz < 0 ? -dz : dz;
                    for (int dy = -R; dy <= R; ++dy) {
                        const int cy = cqy + dy;
                        if ((unsigned)cy >= GD) continue;
                        const int ay = dy < 0 ? -dy : dy;
                        const int azy = az > ay ? az : ay;
                        for (int dx = -R; dx <= R; ++dx) {
                            const int ax = dx < 0 ? -dx : dx;
                            if ((azy > ax ? azy : ax) != R) continue;
                            const int cx = cqx + dx;
                            if ((unsigned)cx >= GD) continue;
                            const int cell = (cz * GD + cy) * GD + cx;
                            const int s0 = starts[cell], e0 = starts[cell + 1];
                            for (int j = s0; j < e0; ++j) {
                                const float4 m = tbl[j];
                                const float x = KEYX(m);
                                if (x <= thrv) {
                                    const float dc = fmaxf(__fadd_rn(x, q2), 0.0f);
                                    u64 cur = ((u64)__float_as_uint(dc) << 32) |
                                              (unsigned)oidx[j];
                                    // bubble-insert: keep 8 smallest keys
                                    #pragma unroll
                                    for (int jj = 0; jj < KNN; ++jj) {
                                        const u64 lo = k8[jj] < cur ? k8[jj] : cur;
                                        const u64 hi = k8[jj] < cur ? cur : k8[jj];
                                        k8[jj] = lo; cur = hi;
                                    }
                                }
                            }
                        }
                    }
                }
            }
            if (__all(R >= Rdone)) break;
        }

        // ---- weights ----
        float wv[KNN]; int iv[KNN]; float wsum = 0.0f;
        #pragma unroll
        for (int j = 0; j < KNN; ++j) {
            const float d2v = __uint_as_float((unsigned)(k8[j] >> 32));
            iv[j] = (int)(unsigned)(k8[j] & 0xFFFFFFFFu);
            const float w = 1.0f / (sqrtf(d2v) + 1e-8f);
            wv[j] = w; wsum += w;
        }
        #pragma unroll
        for (int j = 0; j < KNN; ++j) {
            s_pid[tid][j] = iv[j];
            s_pw[tid][j]  = wv[j] / wsum;
        }
    }
    __syncthreads();

    // ---- gather: full wave, 16 queries x 8 rows, 64 lanes x float4 ----
    const float* fb = sf + (size_t)b * NS * FDIM;
    #pragma unroll 1
    for (int jq = 0; jq < QPB; ++jq) {
        float4 acc = {0.f, 0.f, 0.f, 0.f};
        #pragma unroll
        for (int kk = 0; kk < KNN; ++kk) {
            const int   sid = s_pid[jq][kk];
            const float wk  = s_pw[jq][kk];
            const float4 v = ((const float4*)(fb + (size_t)sid * FDIM))[tid];
            acc.x += wk * v.x; acc.y += wk * v.y;
            acc.z += wk * v.z; acc.w += wk * v.w;
        }
        ((float4*)(out + (size_t)(q0 + jq) * FDIM))[tid] = acc;
    }
}

// ================= fallback: round-6 brute-force kernel (ws too small) =======
#define FG    16
#define FQL   2
#define FNT   512
#define FGRP  (FNT / FG)
#define FQPB  (FGRP * FQL)
#define FSCAN (NS / FG)
#define FCAP  16

#define FKEYX(m, qq) __fmaf_rn(fqx[qq], (m).x, \
                     __fmaf_rn(fqy[qq], (m).y, \
                     __fmaf_rn(fqz[qq], (m).z, (m).w)))

__global__ __launch_bounds__(FNT, 4) void idw_fallback(
    const float* __restrict__ qc, const float* __restrict__ sc,
    const float* __restrict__ sf, float* __restrict__ out)
{
    __shared__ float4 s_m[NS];
    __shared__ u64    s_items[FQPB * FCAP];
    __shared__ int    s_cnt[FQPB];
    __shared__ int    s_idx[FQPB * KNN];
    __shared__ float  s_w[FQPB * KNN];

    const int tid = threadIdx.x;
    const int p   = blockIdx.x;
    const int b   = (p >> 1) & 3;
    const int sub = ((p >> 3) << 1) | (p & 1);
    const int q0  = b * NQ + sub * FQPB;

    for (int s = tid; s < NS; s += FNT) {
        const float sx = sc[3*s+0], sy = sc[3*s+1], sz = sc[3*s+2];
        const float s2 = __fmaf_rn(sx, sx, __fmaf_rn(sy, sy, __fmul_rn(sz, sz)));
        s_m[s] = make_float4(-2.0f*sx, -2.0f*sy, -2.0f*sz, s2);
    }
    if (tid < FQPB) s_cnt[tid] = 0;
    __syncthreads();

    const int g = tid >> 4, l = tid & 15;
    float fqx[FQL], fqy[FQL], fqz[FQL], fq2[FQL];
    #pragma unroll
    for (int qq = 0; qq < FQL; ++qq) {
        const float* qp = qc + (size_t)(q0 + g * FQL + qq) * 3;
        fqx[qq] = qp[0]; fqy[qq] = qp[1]; fqz[qq] = qp[2];
        fq2[qq] = __fmaf_rn(fqx[qq], fqx[qq],
                  __fmaf_rn(fqy[qq], fqy[qq], __fmul_rn(fqz[qq], fqz[qq])));
    }

    float kd[FQL][KNN];
    #pragma unroll
    for (int qq = 0; qq < FQL; ++qq)
        #pragma unroll
        for (int j = 0; j < KNN; ++j) kd[qq][j] = 3.4e38f;

    #pragma unroll 2
    for (int t = 0; t < FSCAN; ++t) {
        const float4 m = s_m[t * FG + l];
        #pragma unroll
        for (int qq = 0; qq < FQL; ++qq) {
            const float x = FKEYX(m, qq);
            const float nk0 = fminf(kd[qq][0], x);
            #pragma unroll
            for (int j = KNN - 1; j >= 1; --j)
                kd[qq][j] = med3(kd[qq][j-1], kd[qq][j], x);
            kd[qq][0] = nk0;
        }
    }

    float thr[FQL];
    #pragma unroll
    for (int qq = 0; qq < FQL; ++qq) {
        float th = 3.4e38f;
        #pragma unroll
        for (int r = 0; r < KNN; ++r) {
            float m = kd[qq][0];
            m = fminf(m, __shfl_xor(m, 1, 64));
            m = fminf(m, __shfl_xor(m, 2, 64));
            m = fminf(m, __shfl_xor(m, 4, 64));
            m = fminf(m, __shfl_xor(m, 8, 64));
            const bool pop = (kd[qq][0] == m);
            #pragma unroll
            for (int j = 0; j < KNN - 1; ++j) kd[qq][j] = pop ? kd[qq][j+1] : kd[qq][j];
            kd[qq][KNN-1] = pop ? 3.4e38f : kd[qq][KNN-1];
            th = m;
        }
        thr[qq] = th;
    }

    #pragma unroll 2
    for (int t = 0; t < FSCAN; ++t) {
        const int s = t * FG + l;
        const float4 m = s_m[s];
        #pragma unroll
        for (int qq = 0; qq < FQL; ++qq) {
            const float x = FKEYX(m, qq);
            if (x <= thr[qq]) {
                const float dc = fmaxf(__fadd_rn(x, fq2[qq]), 0.0f);
                const u64 key = ((u64)__float_as_uint(dc) << 32) | (unsigned)s;
                const int qid = g * FQL + qq;
                const int pos = atomicAdd(&s_cnt[qid], 1);
                if (pos < FCAP) s_items[qid * FCAP + pos] = key;
            }
        }
    }
    __syncthreads();

    if (l < FQL) {
        const int qid = g * FQL + l;
        int cnt = s_cnt[qid];
        if (cnt > KNN) {
            cnt = cnt < FCAP ? cnt : FCAP;
            u64 best[KNN];
            #pragma unroll
            for (int j = 0; j < KNN; ++j) best[j] = ~0ull;
            for (int i = 0; i < cnt; ++i) {
                u64 cur = s_items[qid * FCAP + i];
                #pragma unroll
                for (int j = 0; j < KNN; ++j) {
                    const u64 lo = best[j] < cur ? best[j] : cur;
                    const u64 hi = best[j] < cur ? cur : best[j];
                    best[j] = lo; cur = hi;
                }
            }
            #pragma unroll
            for (int j = 0; j < KNN; ++j) s_items[qid * FCAP + j] = best[j];
        }
    }
    __syncthreads();

    {
        const int qq  = l >> 3;
        const int k   = l & 7;
        const int qid = g * FQL + qq;
        const u64 key = s_items[qid * FCAP + k];
        const float d2v = __uint_as_float((unsigned)(key >> 32));
        const int   idx = (int)(unsigned)(key & 0xFFFFFFFFu);
        const float w   = 1.0f / (sqrtf(d2v) + 1e-8f);
        float ws = w;
        ws += __shfl_xor(ws, 1, 64);
        ws += __shfl_xor(ws, 2, 64);
        ws += __shfl_xor(ws, 4, 64);
        s_idx[qid * KNN + k] = idx;
        s_w  [qid * KNN + k] = w / ws;
    }
    __syncthreads();

    const int wave = tid >> 6, lane = tid & 63;
    const float* fb = sf + (size_t)b * NS * FDIM;
    #pragma unroll 1
    for (int j = 0; j < FQPB / 8; ++j) {
        const int ql = wave * (FQPB / 8) + j;
        float4 acc = {0.f, 0.f, 0.f, 0.f};
        #pragma unroll
        for (int kk = 0; kk < KNN; ++kk) {
            const int   sid = s_idx[ql * KNN + kk];
            const float wk  = s_w  [ql * KNN + kk];
            const float4 v = ((const float4*)(fb + (size_t)sid * FDIM))[lane];
            acc.x += wk * v.x; acc.y += wk * v.y;
            acc.z += wk * v.z; acc.w += wk * v.w;
        }
        ((float4*)(out + (size_t)(q0 + ql) * FDIM))[lane] = acc;
    }
}

extern "C" void kernel_launch(void* const* d_in, const int* in_sizes, int n_in,
                              void* d_out, int out_size, void* d_ws, size_t ws_size,
                              hipStream_t stream) {
    const float* qc = (const float*)d_in[0];   // query_coords  (4,8192,3)
    const float* sc = (const float*)d_in[1];   // sensor_coords (4096,3)
    const float* sf = (const float*)d_in[2];   // sensor_features (4,4096,256)
    float* out = (float*)d_out;                // (4,8192,256)

    if (ws_size >= (size_t)WS_NEED) {
        char* ws = (char*)d_ws;
        int*    starts = (int*)(ws + WS_STARTS);
        float4* tbl    = (float4*)(ws + WS_TABLE);
        int*    oidx   = (int*)(ws + WS_OIDX);
        build_grid<<<1, 1024, 0, stream>>>(sc, starts, tbl, oidx);
        knn_gather<<<(BB * NQ) / QPB, 64, 0, stream>>>(qc, sf, starts, tbl, oidx, out);
    } else {
        idw_fallback<<<(BB * NQ) / FQPB, FNT, 0, stream>>>(qc, sc, sf, out);
    }
}

// Round 8
// 120.687 us; speedup vs baseline: 6.4660x; 6.4660x over previous
//
#include <hip/hip_runtime.h>
#include <hip/hip_bf16.h>
#include <stdint.h>

#define BB    4
#define NQ    8192
#define NS    4096
#define FDIM  256
#define KNN   8
#define QPB   32                 // queries per block
#define CAP   40                 // candidate capacity per query
#define MARGIN 0.0035f           // > 2x bf16-split error bound (~1.1e-3)
#define NSH   (NS / 2)           // sensors per half (wave pair splits range)
#define TILES (NSH / 16)         // 128 MFMA tiles per half

typedef unsigned long long u64;
typedef __attribute__((ext_vector_type(8))) short bf16x8;   // 8 bf16 (4 VGPR)
typedef __attribute__((ext_vector_type(4))) float f32x4;

__device__ __forceinline__ float med3(float a, float b, float c) {
    return __builtin_amdgcn_fmed3f(a, b, c);
}
__device__ __forceinline__ unsigned short f2bf(float v) {
    __hip_bfloat16 h = __float2bfloat16(v);
    return *reinterpret_cast<unsigned short*>(&h);
}
__device__ __forceinline__ float bf2f(unsigned short u) {
    __hip_bfloat16 h;
    *reinterpret_cast<unsigned short*>(&h) = u;
    return __bfloat162float(h);
}

// ============ build: per-sensor K-vector table [NS][16] bf16 (128 KB) ============
// k: 0:s2_hi 1:s2_lo 2:mx_hi 3:mx_lo 4:mx_hi 5:my_hi 6:my_lo 7:my_hi
//    8:mz_hi 9:mz_lo 10:mz_hi 11..15:0        (m* = -2*coord)
__global__ __launch_bounds__(256) void build_tbl(const float* __restrict__ sc,
                                                 unsigned short* __restrict__ tbl) {
    const int s = blockIdx.x * 256 + threadIdx.x;
    if (s >= NS) return;
    const float sx = sc[3*s], sy = sc[3*s+1], sz = sc[3*s+2];
    const float s2 = __fmaf_rn(sx, sx, __fmaf_rn(sy, sy, __fmul_rn(sz, sz)));
    const float mx = -2.0f*sx, my = -2.0f*sy, mz = -2.0f*sz;
    unsigned short e[16];
    #pragma unroll
    for (int j = 0; j < 16; ++j) e[j] = 0;
    unsigned short h, l;
    h = f2bf(s2); l = f2bf(s2 - bf2f(h)); e[0] = h; e[1] = l;
    h = f2bf(mx); l = f2bf(mx - bf2f(h)); e[2] = h; e[3] = l; e[4]  = h;
    h = f2bf(my); l = f2bf(my - bf2f(h)); e[5] = h; e[6] = l; e[7]  = h;
    h = f2bf(mz); l = f2bf(mz - bf2f(h)); e[8] = h; e[9] = l; e[10] = h;
    #pragma unroll
    for (int j = 0; j < 16; ++j) tbl[s * 16 + j] = e[j];
}

// ============ main: MFMA scan -> threshold -> candidates -> exact refine ============
__global__ __launch_bounds__(256, 4) void knn_mfma(
    const float* __restrict__ qc, const float* __restrict__ sc,
    const float* __restrict__ sf, const unsigned short* __restrict__ tbl,
    float* __restrict__ out)
{
    __shared__ unsigned short s_qvec[QPB][32];   // query K-vectors (zeros k11..31)
    __shared__ float4 s_q[QPB];                  // qx,qy,qz,q2 (f32, for refine)
    __shared__ float  s_thr[QPB][2];
    __shared__ int    s_cnt[QPB];
    __shared__ int    s_cand[QPB][CAP];
    __shared__ int    s_idx[QPB][KNN];
    __shared__ float  s_w[QPB][KNN];

    const int tid = threadIdx.x;

    // XCD swizzle: batch b -> XCD pair {2b,2b+1}; bijective over 1024 blocks.
    const int p   = blockIdx.x;
    const int b   = (p >> 1) & 3;
    const int sub = ((p >> 3) << 1) | (p & 1);   // 0..255
    const int q0  = b * NQ + sub * QPB;

    // ---- stage query K-vectors + f32 coords ----
    if (tid < QPB) {
        const float* qp = qc + (size_t)(q0 + tid) * 3;
        const float qx = qp[0], qy = qp[1], qz = qp[2];
        const float q2 = __fmaf_rn(qx, qx, __fmaf_rn(qy, qy, __fmul_rn(qz, qz)));
        s_q[tid] = make_float4(qx, qy, qz, q2);
        #pragma unroll
        for (int j = 11; j < 32; ++j) s_qvec[tid][j] = 0;
        const unsigned short one = f2bf(1.0f);
        unsigned short h, l;
        s_qvec[tid][0] = one; s_qvec[tid][1] = one;
        h = f2bf(qx); l = f2bf(qx - bf2f(h));
        s_qvec[tid][2] = h; s_qvec[tid][3] = h; s_qvec[tid][4]  = l;
        h = f2bf(qy); l = f2bf(qy - bf2f(h));
        s_qvec[tid][5] = h; s_qvec[tid][6] = h; s_qvec[tid][7]  = l;
        h = f2bf(qz); l = f2bf(qz - bf2f(h));
        s_qvec[tid][8] = h; s_qvec[tid][9] = h; s_qvec[tid][10] = l;
        s_cnt[tid] = 0;
    }
    __syncthreads();

    const int wid  = tid >> 6;        // wave 0..3
    const int lane = tid & 63;
    const int pair = wid >> 1;        // query group 0..1
    const int half = wid & 1;         // sensor half
    const int kc   = lane >> 4;       // k-chunk 0..3
    const int qn   = lane & 15;       // query col within tile
    const int qloc = pair * 16 + qn;

    // B fragment: col = lane&15 (query), k = 8*(lane>>4)+i
    const bf16x8 bfrag = *reinterpret_cast<const bf16x8*>(&s_qvec[qloc][kc * 8]);
    const f32x4 zero = {0.f, 0.f, 0.f, 0.f};

    // A fragment source: row = lane&15 (sensor in tile), k-chunks 0..1 real
    const unsigned short* abase =
        tbl + ((size_t)(half * NSH + qn) * 16 + (kc & 1) * 8);

    // ---- pass A: per-lane value-only top-8 via med3 insert ----
    float kd[KNN];
    #pragma unroll
    for (int j = 0; j < KNN; ++j) kd[j] = 3.4e38f;

    bf16x8 a = {};
    if (kc < 2) a = *reinterpret_cast<const bf16x8*>(abase);
    for (int t = 0; t < TILES; ++t) {
        bf16x8 an = {};
        const int tn = (t + 1) & (TILES - 1);
        if (kc < 2) an = *reinterpret_cast<const bf16x8*>(abase + tn * 256);
        const f32x4 d = __builtin_amdgcn_mfma_f32_16x16x32_bf16(a, bfrag, zero, 0, 0, 0);
        #pragma unroll
        for (int r = 0; r < 4; ++r) {
            const float x = d[r];
            const float nk0 = fminf(kd[0], x);
            #pragma unroll
            for (int j = KNN - 1; j >= 1; --j) kd[j] = med3(kd[j-1], kd[j], x);
            kd[0] = nk0;
        }
        a = an;
    }

    // ---- merge 4 lanes per query (xor 16,32): approx 8th-smallest of half ----
    float th = 3.4e38f;
    #pragma unroll
    for (int r = 0; r < KNN; ++r) {
        float m = kd[0];
        m = fminf(m, __shfl_xor(m, 16, 64));
        m = fminf(m, __shfl_xor(m, 32, 64));
        const bool pop = (kd[0] == m);   // over-pop on ties only RAISES th (safe)
        #pragma unroll
        for (int j = 0; j < KNN - 1; ++j) kd[j] = pop ? kd[j+1] : kd[j];
        kd[KNN-1] = pop ? 3.4e38f : kd[KNN-1];
        th = m;
    }
    if (lane < 16) s_thr[qloc][half] = th;
    __syncthreads();

    // min of half-thresholds + margin: provable superset of exact top-8
    const float thr_eff = fminf(s_thr[qloc][0], s_thr[qloc][1]) + MARGIN;

    // ---- pass C: bit-identical MFMA recompute; collect candidate ids ----
    #pragma unroll 2
    for (int t = 0; t < TILES; ++t) {
        bf16x8 ac = {};
        if (kc < 2) ac = *reinterpret_cast<const bf16x8*>(abase + t * 256);
        const f32x4 d = __builtin_amdgcn_mfma_f32_16x16x32_bf16(ac, bfrag, zero, 0, 0, 0);
        #pragma unroll
        for (int r = 0; r < 4; ++r) {
            if (d[r] <= thr_eff) {   // C row = (lane>>4)*4+r = sensor in tile
                const int sid = half * NSH + t * 16 + kc * 4 + r;
                const int pos = atomicAdd(&s_cnt[qloc], 1);
                if (pos < CAP) s_cand[qloc][pos] = sid;
            }
        }
    }
    __syncthreads();

    // ---- exact refine (f32, same arithmetic as rounds 3-6) + weights ----
    if (tid < QPB) {
        const float qx = s_q[tid].x, qy = s_q[tid].y, qz = s_q[tid].z, q2 = s_q[tid].w;
        int cnt = s_cnt[tid]; cnt = cnt < CAP ? cnt : CAP;
        u64 best[KNN];
        #pragma unroll
        for (int j = 0; j < KNN; ++j) best[j] = ~0ull;
        for (int i = 0; i < cnt; ++i) {
            const int sid = s_cand[tid][i];
            const float sx = sc[3*sid], sy = sc[3*sid+1], sz = sc[3*sid+2];
            const float s2 = __fmaf_rn(sx, sx, __fmaf_rn(sy, sy, __fmul_rn(sz, sz)));
            const float x  = __fmaf_rn(qx, -2.0f*sx,
                             __fmaf_rn(qy, -2.0f*sy,
                             __fmaf_rn(qz, -2.0f*sz, s2)));
            const float d2 = fmaxf(__fadd_rn(x, q2), 0.0f);
            u64 cur = ((u64)__float_as_uint(d2) << 32) | (unsigned)sid;
            #pragma unroll
            for (int j = 0; j < KNN; ++j) {
                const u64 lo = best[j] < cur ? best[j] : cur;
                const u64 hi = best[j] < cur ? cur : best[j];
                best[j] = lo; cur = hi;
            }
        }
        float wv[KNN]; float wsum = 0.0f;
        #pragma unroll
        for (int j = 0; j < KNN; ++j) {
            const float d2v = __uint_as_float((unsigned)(best[j] >> 32));
            wv[j] = 1.0f / (sqrtf(d2v) + 1e-8f);
            wsum += wv[j];
            s_idx[tid][j] = (int)(unsigned)(best[j] & 0xFFFFFFFFu);
        }
        #pragma unroll
        for (int j = 0; j < KNN; ++j) s_w[tid][j] = wv[j] / wsum;
    }
    __syncthreads();

    // ---- gather: wave wid handles queries wid*8..+7; 64 lanes x float4 ----
    const float* fb = sf + (size_t)b * NS * FDIM;
    #pragma unroll 1
    for (int jq = 0; jq < QPB / 4; ++jq) {
        const int ql = wid * (QPB / 4) + jq;
        float4 acc = {0.f, 0.f, 0.f, 0.f};
        #pragma unroll
        for (int kk = 0; kk < KNN; ++kk) {
            const int   sid = s_idx[ql][kk];
            const float wk  = s_w[ql][kk];
            const float4 v = ((const float4*)(fb + (size_t)sid * FDIM))[lane];
            acc.x += wk * v.x; acc.y += wk * v.y;
            acc.z += wk * v.z; acc.w += wk * v.w;
        }
        ((float4*)(out + (size_t)(q0 + ql) * FDIM))[lane] = acc;
    }
}

// ================= fallback (round-6 kernel) if workspace too small =================
#define FG    16
#define FQL   2
#define FNT   512
#define FGRP  (FNT / FG)
#define FQPB  (FGRP * FQL)
#define FSCAN (NS / FG)
#define FCAP  16

#define FKEYX(m, qq) __fmaf_rn(fqx[qq], (m).x, \
                     __fmaf_rn(fqy[qq], (m).y, \
                     __fmaf_rn(fqz[qq], (m).z, (m).w)))

__global__ __launch_bounds__(FNT, 4) void idw_fallback(
    const float* __restrict__ qc, const float* __restrict__ sc,
    const float* __restrict__ sf, float* __restrict__ out)
{
    __shared__ float4 s_m[NS];
    __shared__ u64    s_items[FQPB * FCAP];
    __shared__ int    s_cnt[FQPB];
    __shared__ int    s_idx[FQPB * KNN];
    __shared__ float  s_w[FQPB * KNN];

    const int tid = threadIdx.x;
    const int p   = blockIdx.x;
    const int b   = (p >> 1) & 3;
    const int sub = ((p >> 3) << 1) | (p & 1);
    const int q0  = b * NQ + sub * FQPB;

    for (int s = tid; s < NS; s += FNT) {
        const float sx = sc[3*s+0], sy = sc[3*s+1], sz = sc[3*s+2];
        const float s2 = __fmaf_rn(sx, sx, __fmaf_rn(sy, sy, __fmul_rn(sz, sz)));
        s_m[s] = make_float4(-2.0f*sx, -2.0f*sy, -2.0f*sz, s2);
    }
    if (tid < FQPB) s_cnt[tid] = 0;
    __syncthreads();

    const int g = tid >> 4, l = tid & 15;
    float fqx[FQL], fqy[FQL], fqz[FQL], fq2[FQL];
    #pragma unroll
    for (int qq = 0; qq < FQL; ++qq) {
        const float* qp = qc + (size_t)(q0 + g * FQL + qq) * 3;
        fqx[qq] = qp[0]; fqy[qq] = qp[1]; fqz[qq] = qp[2];
        fq2[qq] = __fmaf_rn(fqx[qq], fqx[qq],
                  __fmaf_rn(fqy[qq], fqy[qq], __fmul_rn(fqz[qq], fqz[qq])));
    }

    float kd[FQL][KNN];
    #pragma unroll
    for (int qq = 0; qq < FQL; ++qq)
        #pragma unroll
        for (int j = 0; j < KNN; ++j) kd[qq][j] = 3.4e38f;

    #pragma unroll 2
    for (int t = 0; t < FSCAN; ++t) {
        const float4 m = s_m[t * FG + l];
        #pragma unroll
        for (int qq = 0; qq < FQL; ++qq) {
            const float x = FKEYX(m, qq);
            const float nk0 = fminf(kd[qq][0], x);
            #pragma unroll
            for (int j = KNN - 1; j >= 1; --j)
                kd[qq][j] = med3(kd[qq][j-1], kd[qq][j], x);
            kd[qq][0] = nk0;
        }
    }

    float thr[FQL];
    #pragma unroll
    for (int qq = 0; qq < FQL; ++qq) {
        float thv = 3.4e38f;
        #pragma unroll
        for (int r = 0; r < KNN; ++r) {
            float m = kd[qq][0];
            m = fminf(m, __shfl_xor(m, 1, 64));
            m = fminf(m, __shfl_xor(m, 2, 64));
            m = fminf(m, __shfl_xor(m, 4, 64));
            m = fminf(m, __shfl_xor(m, 8, 64));
            const bool pop = (kd[qq][0] == m);
            #pragma unroll
            for (int j = 0; j < KNN - 1; ++j) kd[qq][j] = pop ? kd[qq][j+1] : kd[qq][j];
            kd[qq][KNN-1] = pop ? 3.4e38f : kd[qq][KNN-1];
            thv = m;
        }
        thr[qq] = thv;
    }

    #pragma unroll 2
    for (int t = 0; t < FSCAN; ++t) {
        const int s = t * FG + l;
        const float4 m = s_m[s];
        #pragma unroll
        for (int qq = 0; qq < FQL; ++qq) {
            const float x = FKEYX(m, qq);
            if (x <= thr[qq]) {
                const float dc = fmaxf(__fadd_rn(x, fq2[qq]), 0.0f);
                const u64 key = ((u64)__float_as_uint(dc) << 32) | (unsigned)s;
                const int qid = g * FQL + qq;
                const int pos = atomicAdd(&s_cnt[qid], 1);
                if (pos < FCAP) s_items[qid * FCAP + pos] = key;
            }
        }
    }
    __syncthreads();

    if (l < FQL) {
        const int qid = g * FQL + l;
        int cnt = s_cnt[qid];
        if (cnt > KNN) {
            cnt = cnt < FCAP ? cnt : FCAP;
            u64 best[KNN];
            #pragma unroll
            for (int j = 0; j < KNN; ++j) best[j] = ~0ull;
            for (int i = 0; i < cnt; ++i) {
                u64 cur = s_items[qid * FCAP + i];
                #pragma unroll
                for (int j = 0; j < KNN; ++j) {
                    const u64 lo = best[j] < cur ? best[j] : cur;
                    const u64 hi = best[j] < cur ? cur : best[j];
                    best[j] = lo; cur = hi;
                }
            }
            #pragma unroll
            for (int j = 0; j < KNN; ++j) s_items[qid * FCAP + j] = best[j];
        }
    }
    __syncthreads();

    {
        const int qq  = l >> 3;
        const int k   = l & 7;
        const int qid = g * FQL + qq;
        const u64 key = s_items[qid * FCAP + k];
        const float d2v = __uint_as_float((unsigned)(key >> 32));
        const int   idx = (int)(unsigned)(key & 0xFFFFFFFFu);
        const float w   = 1.0f / (sqrtf(d2v) + 1e-8f);
        float ws = w;
        ws += __shfl_xor(ws, 1, 64);
        ws += __shfl_xor(ws, 2, 64);
        ws += __shfl_xor(ws, 4, 64);
        s_idx[qid * KNN + k] = idx;
        s_w  [qid * KNN + k] = w / ws;
    }
    __syncthreads();

    const int wave = tid >> 6, lane = tid & 63;
    const float* fb = sf + (size_t)b * NS * FDIM;
    #pragma unroll 1
    for (int j = 0; j < FQPB / 8; ++j) {
        const int ql = wave * (FQPB / 8) + j;
        float4 acc = {0.f, 0.f, 0.f, 0.f};
        #pragma unroll
        for (int kk = 0; kk < KNN; ++kk) {
            const int   sid = s_idx[ql * KNN + kk];
            const float wk  = s_w  [ql * KNN + kk];
            const float4 v = ((const float4*)(fb + (size_t)sid * FDIM))[lane];
            acc.x += wk * v.x; acc.y += wk * v.y;
            acc.z += wk * v.z; acc.w += wk * v.w;
        }
        ((float4*)(out + (size_t)(q0 + ql) * FDIM))[lane] = acc;
    }
}

extern "C" void kernel_launch(void* const* d_in, const int* in_sizes, int n_in,
                              void* d_out, int out_size, void* d_ws, size_t ws_size,
                              hipStream_t stream) {
    const float* qc = (const float*)d_in[0];   // query_coords  (4,8192,3)
    const float* sc = (const float*)d_in[1];   // sensor_coords (4096,3)
    const float* sf = (const float*)d_in[2];   // sensor_features (4,4096,256)
    float* out = (float*)d_out;                // (4,8192,256)

    const size_t tbl_bytes = (size_t)NS * 16 * sizeof(unsigned short);  // 128 KB
    if (ws_size >= tbl_bytes) {
        unsigned short* tbl = (unsigned short*)d_ws;
        build_tbl<<<NS / 256, 256, 0, stream>>>(sc, tbl);
        knn_mfma<<<(BB * NQ) / QPB, 256, 0, stream>>>(qc, sc, sf, tbl, out);
    } else {
        idw_fallback<<<(BB * NQ) / FQPB, FNT, 0, stream>>>(qc, sc, sf, out);
    }
}